// Round 3
// baseline (998.059 us; speedup 1.0000x reference)
//
#include <hip/hip_runtime.h>

// LSTM I=16, H=32, B=8192, T=512, fp32.
// Wave = one batch row. Lane l owns gate rows jA=l, jB=l+64
// (l<32: i,g of unit l; l>=32: f,o of unit l-32).
// 96 weight floats/lane held in VGPRs, PINNED with an opaque asm barrier so
// the scheduler cannot rematerialize the invariant loads inside the loop
// (R2: VGPR=72 proved weights were being re-loaded from L1 every step).
// 4 independent packed-FMA accumulator chains. Branchless activations.
// h double-buffered in LDS, barrier-free (wave-private region, in-order DS).

typedef float v2f __attribute__((ext_vector_type(2)));

constexpr int ISZ = 16, HSZ = 32, TT = 512, BB = 8192;
constexpr int RPB = 4;            // rows per 256-thread block
constexpr int TCH = 32;           // timesteps per staged x chunk
constexpr int NCH = TT / TCH;     // 16
constexpr int F4R = TT * ISZ / 4; // 2048 float4 per row
constexpr int F4C = TCH * ISZ / 4;// 128 float4 per chunk

__device__ __forceinline__ float fsig(float x) {
  // sigmoid(x) = 1/(1+2^(-x*log2e))
  return __builtin_amdgcn_rcpf(1.0f + __builtin_amdgcn_exp2f(-1.4426950408889634f * x));
}
__device__ __forceinline__ v2f pf(v2f a, v2f b, v2f c) {
  return __builtin_elementwise_fma(a, b, c);
}
__device__ __forceinline__ v2f lo2(float4 v) { return (v2f){v.x, v.y}; }
__device__ __forceinline__ v2f hi2(float4 v) { return (v2f){v.z, v.w}; }

__global__ __launch_bounds__(256, 3) void lstm_kernel(
    const float* __restrict__ x, const float* __restrict__ W_ih,
    const float* __restrict__ W_hh, const float* __restrict__ b_ih,
    const float* __restrict__ b_hh, const float* __restrict__ W_fc,
    const float* __restrict__ b_fc, float* __restrict__ out) {
  __shared__ float xs[RPB][2][TCH * ISZ];  // 16 KB
  __shared__ float hbuf[RPB][2][HSZ];      // 1 KB

  const int tid = threadIdx.x;
  const int r = tid >> 6;
  const int l = tid & 63;
  const int row = blockIdx.x * RPB + r;
  const bool lo = (l < 32);
  const int jA = l;
  const int jB = l + 64;

  // ---- load weights: 48 v2f per lane ----
  v2f wihA[8], wihB[8], whhA[16], whhB[16];
  {
    const float4* pa = (const float4*)(W_ih + jA * ISZ);
    const float4* pb = (const float4*)(W_ih + jB * ISZ);
#pragma unroll
    for (int q = 0; q < 4; ++q) {
      float4 va = pa[q], vb = pb[q];
      wihA[2 * q] = lo2(va); wihA[2 * q + 1] = hi2(va);
      wihB[2 * q] = lo2(vb); wihB[2 * q + 1] = hi2(vb);
    }
    const float4* ha = (const float4*)(W_hh + jA * HSZ);
    const float4* hc = (const float4*)(W_hh + jB * HSZ);
#pragma unroll
    for (int q = 0; q < 8; ++q) {
      float4 va = ha[q], vb = hc[q];
      whhA[2 * q] = lo2(va); whhA[2 * q + 1] = hi2(va);
      whhB[2 * q] = lo2(vb); whhB[2 * q + 1] = hi2(vb);
    }
  }
  // PIN: make weight values opaque -> must stay resident in VGPRs, cannot be
  // rematerialized as in-loop global reloads.
#pragma unroll
  for (int q = 0; q < 8; ++q) {
    asm volatile("" : "+v"(wihA[q]), "+v"(wihB[q]));
  }
#pragma unroll
  for (int q = 0; q < 16; ++q) {
    asm volatile("" : "+v"(whhA[q]), "+v"(whhB[q]));
  }

  const float bA = b_ih[jA] + b_hh[jA];
  const float bB = b_ih[jB] + b_hh[jB];
  // gate-B activation constants: lo (g-gate): tanh(x)=2*sig(2x)-1; hi (o): sig(x)
  const float kmul = lo ? 2.0f : 1.0f;
  const float ksc  = lo ? 2.0f : 1.0f;
  const float koff = lo ? -1.0f : 0.0f;
  const float wfc  = lo ? W_fc[l] : 0.0f;

  if (lo) hbuf[r][0][l] = 0.0f;

  float c = 0.0f, hcur = 0.0f;
  int bufx = 0;

  const float4* x4 = (const float4*)x;
  const size_t xbase = (size_t)row * F4R;
  float4 p0 = x4[xbase + 2 * l];
  float4 p1 = x4[xbase + 2 * l + 1];

  auto step = [&](const float4* xv4, const float* hin, float* hout) {
    v2f a0 = (v2f){bA, 0.0f}, a1 = (v2f){0.0f, 0.0f};
    v2f b0 = (v2f){bB, 0.0f}, b1 = (v2f){0.0f, 0.0f};
#pragma unroll
    for (int q = 0; q < 4; ++q) {
      float4 xv = xv4[q];                  // wave-broadcast LDS read
      v2f xl = lo2(xv), xh = hi2(xv);
      a0 = pf(xl, wihA[2 * q], a0);
      a1 = pf(xh, wihA[2 * q + 1], a1);
      b0 = pf(xl, wihB[2 * q], b0);
      b1 = pf(xh, wihB[2 * q + 1], b1);
    }
    const float4* h4 = (const float4*)hin;
#pragma unroll
    for (int q = 0; q < 8; ++q) {
      float4 hv = h4[q];                   // wave-broadcast LDS read
      v2f hl = lo2(hv), hh = hi2(hv);
      a0 = pf(hl, whhA[2 * q], a0);
      a1 = pf(hh, whhA[2 * q + 1], a1);
      b0 = pf(hl, whhB[2 * q], b0);
      b1 = pf(hh, whhB[2 * q + 1], b1);
    }
    const v2f as = a0 + a1, bs = b0 + b1;
    const float gA = as.x + as.y;
    const float gB = bs.x + bs.y;
    const float sA = fsig(gA);                            // sig(i) | sig(f)
    const float sB = fsig(gB * kmul);
    const float tB = __builtin_fmaf(sB, ksc, koff);       // tanh(g) | sig(o)
    const float fO = __shfl_xor(sA, 32, 64);
    const float oO = __shfl_xor(tB, 32, 64);
    c = fO * c + sA * tB;
    const float th = __builtin_fmaf(fsig(c + c), 2.0f, -1.0f);  // tanh(c)
    hcur = oO * th;
    if (lo) hout[l] = hcur;
  };

  for (int ch = 0; ch < NCH; ++ch) {
    float4* xw = (float4*)xs[r][bufx];
    xw[2 * l] = p0;
    xw[2 * l + 1] = p1;
    const int nc = (ch + 1 < NCH) ? ch + 1 : ch;
    p0 = x4[xbase + nc * F4C + 2 * l];
    p1 = x4[xbase + nc * F4C + 2 * l + 1];

    const float4* xrow = (const float4*)xs[r][bufx];
    for (int tl = 0; tl < TCH; tl += 2) {
      step(xrow + 4 * tl,       hbuf[r][0], hbuf[r][1]);
      step(xrow + 4 * (tl + 1), hbuf[r][1], hbuf[r][0]);
    }
    bufx ^= 1;
  }

  // out[row] = sum_k h[k]*W_fc[k] + b_fc  (hi lanes contribute 0 via wfc=0)
  float v = hcur * wfc;
#pragma unroll
  for (int off = 16; off > 0; off >>= 1) v += __shfl_down(v, off, 64);
  if (l == 0) out[row] = v + b_fc[0];
}

extern "C" void kernel_launch(void* const* d_in, const int* in_sizes, int n_in,
                              void* d_out, int out_size, void* d_ws, size_t ws_size,
                              hipStream_t stream) {
  const float* x    = (const float*)d_in[0];
  const float* W_ih = (const float*)d_in[1];
  const float* W_hh = (const float*)d_in[2];
  const float* b_ih = (const float*)d_in[3];
  const float* b_hh = (const float*)d_in[4];
  const float* W_fc = (const float*)d_in[5];
  const float* b_fc = (const float*)d_in[6];
  float* out = (float*)d_out;

  dim3 grid(BB / RPB);
  dim3 block(256);
  lstm_kernel<<<grid, block, 0, stream>>>(x, W_ih, W_hh, b_ih, b_hh, W_fc, b_fc, out);
}

// Round 4
// 855.345 us; speedup vs baseline: 1.1669x; 1.1669x over previous
//
#include <hip/hip_runtime.h>

// LSTM I=16, H=32, B=8192, T=512, fp32 — MFMA (matrix-core) version.
//
// Group = 16 batch rows, handled by a wave PAIR (block = 128 threads).
// Wave hw∈{0,1} owns hidden units u = 16*hw + (lane&15): its 4 MFMA N-blocks
// are gate rows {u, 32+u, 64+u, 96+u} = (i,f,g,o) of unit u, so each lane's
// C-registers hold a complete cell set: 4 rows x 4 gates for ONE unit.
// Cell update is lane-local. h is exchanged via LDS in split-bf16 planes
// (h = h1 + h2), double-buffered, ONE __syncthreads per timestep.
//
// Precision: split-bf16 everywhere. gates = x1@W1 + x2@W1 + x1@W2 (ih)
//          + h1@W1 + h2@W1 + h1@W2 (hh); dropped x2@W2/h2@W2 terms < 1e-4.
// MFMA: v_mfma_f32_16x16x16_bf16 (gfx90a _1k builtin, short4 operands).
//   A: lane holds A[m=lane&15][k=(lane>>4)*4+j]   (j=0..3)
//   B: lane holds B[k=(lane>>4)*4+j][n=lane&15]
//   C/D: lane holds D[row=(lane>>4)*4+reg][col=lane&15]   (verified m89)

typedef short short4v __attribute__((ext_vector_type(4)));
typedef __bf16 bf4 __attribute__((ext_vector_type(4)));
typedef float f4 __attribute__((ext_vector_type(4)));

constexpr int ISZ = 16, HSZ = 32, TT = 512, BB = 8192;
constexpr int LDS_STRIDE = 40;  // bf16 elems per row: 32 + pad -> 80B rows

#define MFMA16(a, b, c) __builtin_amdgcn_mfma_f32_16x16x16bf16_1k((a), (b), (c), 0, 0, 0)

__device__ __forceinline__ float fsig(float x) {
  return __builtin_amdgcn_rcpf(1.0f + __builtin_amdgcn_exp2f(-1.44269504f * x));
}

// split fp32x4 -> hi/lo bf16x4 fragments (RNE split: v = hi + lo + O(2^-16 v))
__device__ __forceinline__ void split4(f4 v, short4v& hi, short4v& lo) {
  bf4 b1, b2;
#pragma unroll
  for (int i = 0; i < 4; ++i) b1[i] = (__bf16)v[i];
#pragma unroll
  for (int i = 0; i < 4; ++i) b2[i] = (__bf16)(v[i] - (float)b1[i]);
  hi = __builtin_bit_cast(short4v, b1);
  lo = __builtin_bit_cast(short4v, b2);
}

__global__ __launch_bounds__(128) void lstm_mfma(
    const float* __restrict__ x, const float* __restrict__ W_ih,
    const float* __restrict__ W_hh, const float* __restrict__ b_ih,
    const float* __restrict__ b_hh, const float* __restrict__ W_fc,
    const float* __restrict__ b_fc, float* __restrict__ out) {
  // h planes: [buf][plane(h1/h2)][row 16][stride 40 bf16] = 5120 B
  __shared__ __align__(16) __bf16 hlds[2][2][16][LDS_STRIDE];

  const int tid = threadIdx.x;
  const int hw = tid >> 6;       // which unit-half this wave owns
  const int L = tid & 63;
  const int m = L & 15;          // M index (row) for A/C; N index (col) for B
  const int q = L >> 4;          // quad
  const int row0 = blockIdx.x * 16;
  const int u = hw * 16 + m;     // hidden unit owned by this lane

  // ---- load + split weights (once) ----
  const int jg[4] = {u, 32 + u, 64 + u, 96 + u};  // gate rows i,f,g,o
  short4v whh1a[4], whh1b[4], whh2a[4], whh2b[4], wih1[4], wih2[4];
  f4 biasv[4];
#pragma unroll
  for (int b = 0; b < 4; ++b) {
    const int j = jg[b];
    f4 wa = *(const f4*)(W_hh + j * HSZ + q * 4);        // k = q*4..q*4+3
    f4 wb = *(const f4*)(W_hh + j * HSZ + 16 + q * 4);   // k = 16+q*4..
    split4(wa, whh1a[b], whh2a[b]);
    split4(wb, whh1b[b], whh2b[b]);
    f4 wi = *(const f4*)(W_ih + j * ISZ + q * 4);
    split4(wi, wih1[b], wih2[b]);
    const float bb = b_ih[j] + b_hh[j];
    biasv[b] = (f4){bb, bb, bb, bb};
  }

  // ---- zero h buffers (h_0 = 0) ----
  for (int i = tid; i < 2 * 2 * 16 * LDS_STRIDE; i += 128)
    ((__bf16*)hlds)[i] = (__bf16)0.0f;
  __syncthreads();

  float cst[4] = {0.0f, 0.0f, 0.0f, 0.0f};

  const float* xrow = x + (size_t)(row0 + m) * TT * ISZ + q * 4;
  f4 xc = *(const f4*)xrow;  // x fragment source for t=0

  for (int t = 0; t < TT; ++t) {
    const int p = t & 1;
    // A-fragments of h_t (issued first; latency hidden by x-split + ih MFMAs)
    const short4v h1a = *(const short4v*)&hlds[p][0][m][q * 4];
    const short4v h1b = *(const short4v*)&hlds[p][0][m][16 + q * 4];
    const short4v h2a = *(const short4v*)&hlds[p][1][m][q * 4];
    const short4v h2b = *(const short4v*)&hlds[p][1][m][16 + q * 4];

    // prefetch next timestep's x
    const int tn = (t < TT - 1) ? t + 1 : t;
    const f4 xn = *(const f4*)(xrow + tn * ISZ);

    short4v x1, x2;
    split4(xc, x1, x2);

    f4 acc[4];
#pragma unroll
    for (int b = 0; b < 4; ++b) {
      f4 a = MFMA16(x1, wih1[b], biasv[b]);
      a = MFMA16(x2, wih1[b], a);
      a = MFMA16(x1, wih2[b], a);
      a = MFMA16(h1a, whh1a[b], a);
      a = MFMA16(h1b, whh1b[b], a);
      a = MFMA16(h2a, whh1a[b], a);
      a = MFMA16(h2b, whh1b[b], a);
      a = MFMA16(h1a, whh2a[b], a);
      a = MFMA16(h1b, whh2b[b], a);
      acc[b] = a;
    }
    xc = xn;

    // ---- cell update: lane owns (rows q*4+r, unit u) ----
#pragma unroll
    for (int r = 0; r < 4; ++r) {
      const float ig = fsig(acc[0][r]);
      const float fg = fsig(acc[1][r]);
      const float gg = 2.0f * fsig(2.0f * acc[2][r]) - 1.0f;  // tanh(g)
      const float og = fsig(acc[3][r]);
      float cc = fg * cst[r] + ig * gg;
      cst[r] = cc;
      const float th = 2.0f * fsig(2.0f * cc) - 1.0f;          // tanh(c)
      const float h = og * th;
      const __bf16 h1 = (__bf16)h;
      const __bf16 h2 = (__bf16)(h - (float)h1);
      const int R = q * 4 + r;
      hlds[p ^ 1][0][R][u] = h1;
      hlds[p ^ 1][1][R][u] = h2;
    }
    __syncthreads();
  }

  // ---- epilogue: out[row] = sum_u h[row][u]*W_fc[u] + b_fc ----
  // final h (t=TT) is in buf[0] (TT even)
  if (tid < 16) {
    float s = b_fc[0];
#pragma unroll 8
    for (int uu = 0; uu < HSZ; ++uu) {
      const float h = (float)hlds[0][0][tid][uu] + (float)hlds[0][1][tid][uu];
      s += h * W_fc[uu];
    }
    out[row0 + tid] = s;
  }
}

extern "C" void kernel_launch(void* const* d_in, const int* in_sizes, int n_in,
                              void* d_out, int out_size, void* d_ws, size_t ws_size,
                              hipStream_t stream) {
  const float* x    = (const float*)d_in[0];
  const float* W_ih = (const float*)d_in[1];
  const float* W_hh = (const float*)d_in[2];
  const float* b_ih = (const float*)d_in[3];
  const float* b_hh = (const float*)d_in[4];
  const float* W_fc = (const float*)d_in[5];
  const float* b_fc = (const float*)d_in[6];
  float* out = (float*)d_out;

  dim3 grid(BB / 16);   // 512 blocks = 512 row-groups
  dim3 block(128);      // wave pair per group
  lstm_mfma<<<grid, block, 0, stream>>>(x, W_ih, W_hh, b_ih, b_hh, W_fc, b_fc, out);
}